// Round 1
// baseline (31713.315 us; speedup 1.0000x reference)
//
#include <hip/hip_runtime.h>

#define HID   1024
#define BATCH 256
#define TSEQ  128
#define PRED  96
#define IND   7
#define OUTD  7
#define SK    10   // small input dim: 7 features + 3 time-encode dims

typedef __attribute__((ext_vector_type(8))) _Float16 f16x8;
typedef __attribute__((ext_vector_type(4))) float    f32x4;

// GEMM tile: gates [BM x BN] per block, BN = 32 units * 4 gates
#define BM   32
#define BN   128
#define BK   64
#define ASTR 72    // LDS row stride (halfs), 144B: 16B-aligned, 2-way-conflict only (free)
#define BSTR 72
#define GSTR 132   // gates LDS stride (floats)

__device__ __forceinline__ float sigmoidf_fast(float x) {
  return 1.0f / (1.0f + __expf(-x));
}
__device__ __forceinline__ float tanhf_fast(float x) {
  float ax = fabsf(x);
  float e  = __expf(-2.0f * ax);
  float r  = (1.0f - e) / (1.0f + e);
  return copysignf(r, x);
}

// ---------------------------------------------------------------------------
// Weight prep: build fp16 B-matrices [n][k] with permuted n:
//   n = nb*128 + gate*32 + u  <->  original row r = gate*1024 + (nb*32 + u)
// L0: K=1024 (Whh0 only; Wih0 kept fp32 as W0p[n][10]).
// L1/L2: K=2048 (k<1024 -> Wih, k>=1024 -> Whh).  biasP[l][n] = bih[r]+bhh[r].
// ---------------------------------------------------------------------------
__global__ __launch_bounds__(256) void prep_kernel(
    const float* __restrict__ Wih0, const float* __restrict__ Whh0,
    const float* __restrict__ bih0, const float* __restrict__ bhh0,
    const float* __restrict__ Wih1, const float* __restrict__ Whh1,
    const float* __restrict__ bih1, const float* __restrict__ bhh1,
    const float* __restrict__ Wih2, const float* __restrict__ Whh2,
    const float* __restrict__ bih2, const float* __restrict__ bhh2,
    _Float16* __restrict__ B0, _Float16* __restrict__ B1, _Float16* __restrict__ B2,
    float* __restrict__ W0p, float* __restrict__ biasP)
{
  size_t e = (size_t)blockIdx.x * 256 + threadIdx.x;
  const size_t S0 = (size_t)4096 * 1024;
  const size_t S1 = (size_t)4096 * 2048;
  if (e < S0) {
    int n = (int)(e >> 10), k = (int)(e & 1023);
    int nb = n >> 7, gate = (n >> 5) & 3, u = n & 31;
    int r = gate * 1024 + nb * 32 + u;
    B0[e] = (_Float16)Whh0[(size_t)r * 1024 + k];
  } else if (e < S0 + S1) {
    size_t q = e - S0;
    int n = (int)(q >> 11), k = (int)(q & 2047);
    int nb = n >> 7, gate = (n >> 5) & 3, u = n & 31;
    int r = gate * 1024 + nb * 32 + u;
    float v = (k < 1024) ? Wih1[(size_t)r * 1024 + k]
                         : Whh1[(size_t)r * 1024 + (k - 1024)];
    B1[q] = (_Float16)v;
  } else if (e < S0 + 2 * S1) {
    size_t q = e - S0 - S1;
    int n = (int)(q >> 11), k = (int)(q & 2047);
    int nb = n >> 7, gate = (n >> 5) & 3, u = n & 31;
    int r = gate * 1024 + nb * 32 + u;
    float v = (k < 1024) ? Wih2[(size_t)r * 1024 + k]
                         : Whh2[(size_t)r * 1024 + (k - 1024)];
    B2[q] = (_Float16)v;
  } else if (e < S0 + 2 * S1 + 40960) {
    int q = (int)(e - S0 - 2 * S1);
    int n = q / 10, k = q - n * 10;
    int nb = n >> 7, gate = (n >> 5) & 3, u = n & 31;
    int r = gate * 1024 + nb * 32 + u;
    W0p[q] = Wih0[(size_t)r * 10 + k];
  } else if (e < S0 + 2 * S1 + 40960 + 12288) {
    int q = (int)(e - S0 - 2 * S1 - 40960);
    int l = q >> 12, n = q & 4095;
    int nb = n >> 7, gate = (n >> 5) & 3, u = n & 31;
    int r = gate * 1024 + nb * 32 + u;
    const float* bi = (l == 0) ? bih0 : (l == 1) ? bih1 : bih2;
    const float* bh = (l == 0) ? bhh0 : (l == 1) ? bhh1 : bhh2;
    biasP[q] = bi[r] + bh[r];
  }
}

// ---------------------------------------------------------------------------
// One LSTM layer-step: gates = [A1|A2] @ B^T (fp16 MFMA, fp32 acc)
//                      (+ small K=10 input part for layer 0, fp32)
//                      + bias, then fused cell update -> c (fp32), h (fp16).
// mode 0: encoder layer0 (small input from x/xte), mode 1: decoder layer0
// (small input from yfb/yte), mode 2: deep layer (K=2048 concat A1,A2).
// Grid: (8 m-tiles, 32 n-tiles), 256 threads (4 waves).
// ---------------------------------------------------------------------------
__global__ __launch_bounds__(256) void lstm_step(
    int mode, int tstep, int Kdim,
    const _Float16* __restrict__ A1, const _Float16* __restrict__ A2,
    const _Float16* __restrict__ Bm, const float* __restrict__ biasL,
    const float* __restrict__ W0p,
    float* __restrict__ cst, _Float16* __restrict__ hout,
    const float* __restrict__ x, const int* __restrict__ xte,
    const float* __restrict__ yfb, const int* __restrict__ yte,
    const float* __restrict__ e0, const float* __restrict__ e1,
    const float* __restrict__ e2, const float* __restrict__ e3)
{
  __shared__ __align__(16) _Float16 As[BM * ASTR];
  __shared__ __align__(16) _Float16 Bs[BN * BSTR];
  __shared__ float Gs[BM * GSTR];
  __shared__ float SmallIn[BM * SK];
  __shared__ float W0s[BN * 11];

  const int tid = threadIdx.x;
  const int mb = blockIdx.x, nb = blockIdx.y;
  const int Mbase = mb * BM;

  if (mode < 2) {
    if (tid < BM) {
      int Mg = Mbase + tid;
      float v[SK];
      if (mode == 0) {
        const float* xp = x + ((size_t)Mg * TSEQ + tstep) * IND;
#pragma unroll
        for (int i = 0; i < IND; ++i) v[i] = xp[i];
        const int* ip = xte + ((size_t)Mg * TSEQ + tstep) * 4;
        int i0 = ip[0], i1 = ip[1], i2 = ip[2], i3 = ip[3];
#pragma unroll
        for (int d = 0; d < 3; ++d)
          v[IND + d] = e0[i0 * 3 + d] + e1[i1 * 3 + d] + e2[i2 * 3 + d] + e3[i3 * 3 + d];
      } else {
        const float* yp = yfb + (size_t)Mg * OUTD;
#pragma unroll
        for (int i = 0; i < OUTD; ++i) v[i] = yp[i];
        const int* ip = yte + ((size_t)Mg * PRED + tstep) * 4;
        int i0 = ip[0], i1 = ip[1], i2 = ip[2], i3 = ip[3];
#pragma unroll
        for (int d = 0; d < 3; ++d)
          v[IND + d] = e0[i0 * 3 + d] + e1[i1 * 3 + d] + e2[i2 * 3 + d] + e3[i3 * 3 + d];
      }
#pragma unroll
      for (int i = 0; i < SK; ++i) SmallIn[tid * SK + i] = v[i];
    }
    if (tid < BN) {
      const float* wp = W0p + (size_t)(nb * BN + tid) * SK;
#pragma unroll
      for (int i = 0; i < SK; ++i) W0s[tid * 11 + i] = wp[i];
    }
  }

  const int w = tid >> 6, lane = tid & 63;
  const int quad = lane >> 4, l16 = lane & 15;

  f32x4 acc[2][2] = {};

  const int a_row = tid >> 3, a_seg = tid & 7;          // A: 32 rows x 8 16B-segs
  const int b_row = tid >> 1, b_seg0 = (tid & 1) * 4;   // B: 128 rows x 8 16B-segs (4/thread)
  const size_t bgbase = (size_t)(nb * BN + b_row) * (size_t)Kdim;

  for (int kk = 0; kk < Kdim; kk += BK) {
    const _Float16* Asrc = (kk < 1024)
        ? (A1 + (size_t)(Mbase + a_row) * HID + kk)
        : (A2 + (size_t)(Mbase + a_row) * HID + (kk - 1024));
    uint4 av = *reinterpret_cast<const uint4*>(Asrc + a_seg * 8);
    uint4 bv[4];
    const _Float16* Bsrc = Bm + bgbase + kk;
#pragma unroll
    for (int i = 0; i < 4; ++i)
      bv[i] = *reinterpret_cast<const uint4*>(Bsrc + (b_seg0 + i) * 8);
    __syncthreads();   // protect previous iteration's fragment reads
    *reinterpret_cast<uint4*>(As + a_row * ASTR + a_seg * 8) = av;
#pragma unroll
    for (int i = 0; i < 4; ++i)
      *reinterpret_cast<uint4*>(Bs + b_row * BSTR + (b_seg0 + i) * 8) = bv[i];
    __syncthreads();
#pragma unroll
    for (int ks = 0; ks < 2; ++ks) {
      f16x8 af[2], bf[2];
#pragma unroll
      for (int mt = 0; mt < 2; ++mt)
        af[mt] = *reinterpret_cast<const f16x8*>(As + (mt * 16 + l16) * ASTR + ks * 32 + quad * 8);
#pragma unroll
      for (int nt = 0; nt < 2; ++nt)
        bf[nt] = *reinterpret_cast<const f16x8*>(Bs + (w * 32 + nt * 16 + l16) * BSTR + ks * 32 + quad * 8);
#pragma unroll
      for (int mt = 0; mt < 2; ++mt)
#pragma unroll
        for (int nt = 0; nt < 2; ++nt)
          acc[mt][nt] = __builtin_amdgcn_mfma_f32_16x16x32_f16(af[mt], bf[nt], acc[mt][nt], 0, 0, 0);
    }
  }

  // acc (C-layout: row = quad*4+r, col = lane&15) -> gates LDS tile
#pragma unroll
  for (int mt = 0; mt < 2; ++mt)
#pragma unroll
    for (int nt = 0; nt < 2; ++nt) {
      int row = mt * 16 + quad * 4;
      int col = w * 32 + nt * 16 + l16;
#pragma unroll
      for (int r = 0; r < 4; ++r)
        Gs[(row + r) * GSTR + col] = acc[mt][nt][r];
    }
  __syncthreads();

  // fused cell update: 32 rows x 32 units, 4 (m,u) pairs per thread
#pragma unroll
  for (int i = 0; i < 4; ++i) {
    int pidx = tid + i * 256;
    int m = pidx >> 5, u = pidx & 31;
    float gi = Gs[m * GSTR + u];
    float gf = Gs[m * GSTR + 32 + u];
    float gg = Gs[m * GSTR + 64 + u];
    float go = Gs[m * GSTR + 96 + u];
    int nbase = nb * BN;
    gi += biasL[nbase + u];
    gf += biasL[nbase + 32 + u];
    gg += biasL[nbase + 64 + u];
    go += biasL[nbase + 96 + u];
    if (mode < 2) {
#pragma unroll
      for (int k = 0; k < SK; ++k) {
        float sv = SmallIn[m * SK + k];
        gi += sv * W0s[u * 11 + k];
        gf += sv * W0s[(32 + u) * 11 + k];
        gg += sv * W0s[(64 + u) * 11 + k];
        go += sv * W0s[(96 + u) * 11 + k];
      }
    }
    size_t cidx = (size_t)(Mbase + m) * HID + (size_t)nb * 32 + u;
    float cold = cst[cidx];
    float cn = sigmoidf_fast(gf) * cold + sigmoidf_fast(gi) * tanhf_fast(gg);
    float hn = sigmoidf_fast(go) * tanhf_fast(cn);
    cst[cidx] = cn;
    hout[cidx] = (_Float16)hn;
  }
}

// ---------------------------------------------------------------------------
// FC head: y = h2 @ fcW^T + fcb -> d_out[:, s, :] and feedback buffer.
// 64 blocks x 4 waves; one wave per batch row.
// ---------------------------------------------------------------------------
__global__ __launch_bounds__(256) void fc_kernel(
    const _Float16* __restrict__ h2, const float* __restrict__ fcW,
    const float* __restrict__ fcb, float* __restrict__ out,
    float* __restrict__ yfb, int s)
{
  int wv = threadIdx.x >> 6, lane = threadIdx.x & 63;
  int row = blockIdx.x * 4 + wv;
  const _Float16* hp = h2 + (size_t)row * HID + lane * 16;
  float hv[16];
#pragma unroll
  for (int i = 0; i < 16; ++i) hv[i] = (float)hp[i];
  float acc[OUTD];
#pragma unroll
  for (int o = 0; o < OUTD; ++o) {
    const float* wp = fcW + (size_t)o * HID + lane * 16;
    float a = 0.f;
#pragma unroll
    for (int i = 0; i < 16; ++i) a += hv[i] * wp[i];
    acc[o] = a;
  }
#pragma unroll
  for (int o = 0; o < OUTD; ++o)
#pragma unroll
    for (int off = 32; off >= 1; off >>= 1)
      acc[o] += __shfl_xor(acc[o], off, 64);
  if (lane == 0) {
#pragma unroll
    for (int o = 0; o < OUTD; ++o) {
      float v = acc[o] + fcb[o];
      out[(size_t)row * (PRED * OUTD) + s * OUTD + o] = v;
      yfb[row * OUTD + o] = v;
    }
  }
}

// ---------------------------------------------------------------------------
// Workspace layout (bytes):
//   B0      @ 0         : 4096*1024*2 = 8388608
//   B1      @ 8388608   : 4096*2048*2 = 16777216
//   B2      @ 25165824  : 16777216
//   W0p     @ 41943040  : 4096*10*4   = 163840
//   biasP   @ 42106880  : 3*4096*4    = 49152
//   h par0  @ 42156032  : 3*256*1024*2 = 1572864   } zeroed together
//   c       @ 43728896  : 3*256*1024*4 = 3145728   } (4718592 B)
//   h par1  @ 46874624  : 1572864
//   yfb     @ 48447488  : 256*7*4 = 7168
// total ~48.5 MB
// ---------------------------------------------------------------------------
extern "C" void kernel_launch(void* const* d_in, const int* in_sizes, int n_in,
                              void* d_out, int out_size, void* d_ws, size_t ws_size,
                              hipStream_t stream) {
  const float* x   = (const float*)d_in[0];
  const int*   xte = (const int*)d_in[2];
  const int*   yte = (const int*)d_in[3];
  const float* e0  = (const float*)d_in[4];
  const float* e1  = (const float*)d_in[5];
  const float* e2  = (const float*)d_in[6];
  const float* e3  = (const float*)d_in[7];
  const float* Wih0 = (const float*)d_in[8];
  const float* Whh0 = (const float*)d_in[9];
  const float* bih0 = (const float*)d_in[10];
  const float* bhh0 = (const float*)d_in[11];
  const float* Wih1 = (const float*)d_in[12];
  const float* Whh1 = (const float*)d_in[13];
  const float* bih1 = (const float*)d_in[14];
  const float* bhh1 = (const float*)d_in[15];
  const float* Wih2 = (const float*)d_in[16];
  const float* Whh2 = (const float*)d_in[17];
  const float* bih2 = (const float*)d_in[18];
  const float* bhh2 = (const float*)d_in[19];
  const float* fcW = (const float*)d_in[20];
  const float* fcb = (const float*)d_in[21];
  float* out = (float*)d_out;

  char* ws = (char*)d_ws;
  _Float16* B0   = (_Float16*)(ws);
  _Float16* B1   = (_Float16*)(ws + 8388608);
  _Float16* B2   = (_Float16*)(ws + 25165824);
  float*    W0p  = (float*)(ws + 41943040);
  float*    biasP= (float*)(ws + 42106880);
  char*     hp0  = ws + 42156032;
  float*    cbuf = (float*)(ws + 43728896);
  char*     hp1  = ws + 46874624;
  float*    yfb  = (float*)(ws + 48447488);

  // zero h (parity 0) + c in one contiguous memset
  hipMemsetAsync(hp0, 0, 4718592, stream);

  // weight prep: 20971520 + 40960 + 12288 = 21024768 elements = 82128 * 256
  prep_kernel<<<82128, 256, 0, stream>>>(Wih0, Whh0, bih0, bhh0,
                                         Wih1, Whh1, bih1, bhh1,
                                         Wih2, Whh2, bih2, bhh2,
                                         B0, B1, B2, W0p, biasP);

  auto hbuf = [&](int par, int l) -> _Float16* {
    return (_Float16*)((par ? hp1 : hp0) + (size_t)l * 524288);
  };
  float* cl[3] = {cbuf, cbuf + 262144, cbuf + 524288};

  dim3 grid(8, 32), blk(256);
  int p = 0;

  // encoder
  for (int t = 0; t < TSEQ; ++t) {
    lstm_step<<<grid, blk, 0, stream>>>(0, t, 1024, hbuf(p, 0), hbuf(p, 0), B0,
                                        biasP, W0p, cl[0], hbuf(1 - p, 0),
                                        x, xte, yfb, yte, e0, e1, e2, e3);
    lstm_step<<<grid, blk, 0, stream>>>(2, t, 2048, hbuf(1 - p, 0), hbuf(p, 1), B1,
                                        biasP + 4096, W0p, cl[1], hbuf(1 - p, 1),
                                        x, xte, yfb, yte, e0, e1, e2, e3);
    lstm_step<<<grid, blk, 0, stream>>>(2, t, 2048, hbuf(1 - p, 1), hbuf(p, 2), B2,
                                        biasP + 8192, W0p, cl[2], hbuf(1 - p, 2),
                                        x, xte, yfb, yte, e0, e1, e2, e3);
    p ^= 1;
  }

  // decoder: fc produces y_s from current h2; then (if more steps) run layers
  for (int s = 0; s < PRED; ++s) {
    fc_kernel<<<64, 256, 0, stream>>>(hbuf(p, 2), fcW, fcb, out, yfb, s);
    if (s < PRED - 1) {
      lstm_step<<<grid, blk, 0, stream>>>(1, s, 1024, hbuf(p, 0), hbuf(p, 0), B0,
                                          biasP, W0p, cl[0], hbuf(1 - p, 0),
                                          x, xte, yfb, yte, e0, e1, e2, e3);
      lstm_step<<<grid, blk, 0, stream>>>(2, s, 2048, hbuf(1 - p, 0), hbuf(p, 1), B1,
                                          biasP + 4096, W0p, cl[1], hbuf(1 - p, 1),
                                          x, xte, yfb, yte, e0, e1, e2, e3);
      lstm_step<<<grid, blk, 0, stream>>>(2, s, 2048, hbuf(1 - p, 1), hbuf(p, 2), B2,
                                          biasP + 8192, W0p, cl[2], hbuf(1 - p, 2),
                                          x, xte, yfb, yte, e0, e1, e2, e3);
      p ^= 1;
    }
  }
}

// Round 2
// 12079.399 us; speedup vs baseline: 2.6254x; 2.6254x over previous
//
#include <hip/hip_runtime.h>

#define HID   1024
#define BATCH 256
#define TSEQ  128
#define PRED  96
#define IND   7
#define OUTD  7
#define SK    10   // small input dim: 7 features + 3 time-encode dims

typedef __attribute__((ext_vector_type(8))) _Float16 f16x8;
typedef __attribute__((ext_vector_type(4))) float    f32x4;

// GEMM tile: gates [BM x BN] per block, BN = 16 units * 4 gates
#define BM   64
#define BN   64
#define BK   128
#define GSTR 68    // gates LDS stride (floats): (m*68+col)%32 spreads 4 m's -> <=2-way

__device__ __forceinline__ float sigmoidf_fast(float x) {
  return 1.0f / (1.0f + __expf(-x));
}
__device__ __forceinline__ float tanhf_fast(float x) {
  float ax = fabsf(x);
  float e  = __expf(-2.0f * ax);
  float r  = (1.0f - e) / (1.0f + e);
  return copysignf(r, x);
}

__device__ __forceinline__ void async_cp16(const void* g, void* l) {
  __builtin_amdgcn_global_load_lds(
      (const __attribute__((address_space(1))) void*)g,
      (__attribute__((address_space(3))) void*)l, 16, 0, 0);
}

// ---------------------------------------------------------------------------
// Weight prep: build fp16 B-matrices [n][k] with permuted n:
//   n = nb*64 + gate*16 + u  <->  original row r = gate*1024 + (nb*16 + u)
// L0: K=1024 (Whh0 only; Wih0 kept fp32 as W0p[n][10]).
// L1/L2: K=2048 (k<1024 -> Wih, k>=1024 -> Whh).  biasP[l][n] = bih[r]+bhh[r].
// ---------------------------------------------------------------------------
__global__ __launch_bounds__(256) void prep_kernel(
    const float* __restrict__ Wih0, const float* __restrict__ Whh0,
    const float* __restrict__ bih0, const float* __restrict__ bhh0,
    const float* __restrict__ Wih1, const float* __restrict__ Whh1,
    const float* __restrict__ bih1, const float* __restrict__ bhh1,
    const float* __restrict__ Wih2, const float* __restrict__ Whh2,
    const float* __restrict__ bih2, const float* __restrict__ bhh2,
    _Float16* __restrict__ B0, _Float16* __restrict__ B1, _Float16* __restrict__ B2,
    float* __restrict__ W0p, float* __restrict__ biasP)
{
  size_t e = (size_t)blockIdx.x * 256 + threadIdx.x;
  const size_t S0 = (size_t)4096 * 1024;
  const size_t S1 = (size_t)4096 * 2048;
  if (e < S0) {
    int n = (int)(e >> 10), k = (int)(e & 1023);
    int nb = n >> 6, gate = (n >> 4) & 3, u = n & 15;
    int r = gate * 1024 + nb * 16 + u;
    B0[e] = (_Float16)Whh0[(size_t)r * 1024 + k];
  } else if (e < S0 + S1) {
    size_t q = e - S0;
    int n = (int)(q >> 11), k = (int)(q & 2047);
    int nb = n >> 6, gate = (n >> 4) & 3, u = n & 15;
    int r = gate * 1024 + nb * 16 + u;
    float v = (k < 1024) ? Wih1[(size_t)r * 1024 + k]
                         : Whh1[(size_t)r * 1024 + (k - 1024)];
    B1[q] = (_Float16)v;
  } else if (e < S0 + 2 * S1) {
    size_t q = e - S0 - S1;
    int n = (int)(q >> 11), k = (int)(q & 2047);
    int nb = n >> 6, gate = (n >> 4) & 3, u = n & 15;
    int r = gate * 1024 + nb * 16 + u;
    float v = (k < 1024) ? Wih2[(size_t)r * 1024 + k]
                         : Whh2[(size_t)r * 1024 + (k - 1024)];
    B2[q] = (_Float16)v;
  } else if (e < S0 + 2 * S1 + 40960) {
    int q = (int)(e - S0 - 2 * S1);
    int n = q / 10, k = q - n * 10;
    int nb = n >> 6, gate = (n >> 4) & 3, u = n & 15;
    int r = gate * 1024 + nb * 16 + u;
    W0p[q] = Wih0[(size_t)r * 10 + k];
  } else if (e < S0 + 2 * S1 + 40960 + 12288) {
    int q = (int)(e - S0 - 2 * S1 - 40960);
    int l = q >> 12, n = q & 4095;
    int nb = n >> 6, gate = (n >> 4) & 3, u = n & 15;
    int r = gate * 1024 + nb * 16 + u;
    const float* bi = (l == 0) ? bih0 : (l == 1) ? bih1 : bih2;
    const float* bh = (l == 0) ? bhh0 : (l == 1) ? bhh1 : bhh2;
    biasP[q] = bi[r] + bh[r];
  }
}

// ---------------------------------------------------------------------------
// One LSTM layer-step: gates = [A1|A2] @ B^T (fp16 MFMA, fp32 acc)
//                      (+ small K=10 input part for layer 0, fp32)
//                      + bias, then fused cell update -> c (fp32), h (fp16).
// mode 0: encoder layer0, mode 1: decoder layer0, mode 2: deep layer (K=2048).
// Grid: (64 n-tiles, 4 m-tiles) -> linear id % 8 == n%8 -> stable n->XCD map,
// weights slice stays L2-resident per XCD across all 224 steps.
// Staging: global_load_lds 16B/lane, XOR-seg swizzle folded into the per-lane
// global gather address -> conflict-free ds_read_b128 fragments.
// ---------------------------------------------------------------------------
__global__ __launch_bounds__(256) void lstm_step(
    int mode, int tstep, int Kdim,
    const _Float16* __restrict__ A1, const _Float16* __restrict__ A2,
    const _Float16* __restrict__ Bm, const float* __restrict__ biasL,
    const float* __restrict__ W0p,
    float* __restrict__ cst, _Float16* __restrict__ hout,
    const float* __restrict__ x, const int* __restrict__ xte,
    const float* __restrict__ yfb, const int* __restrict__ yte,
    const float* __restrict__ e0, const float* __restrict__ e1,
    const float* __restrict__ e2, const float* __restrict__ e3)
{
  // LDS images per BK=128 chunk: row r (0..63) x 16 segs of 16B,
  // image(r, s) holds global seg (s ^ (r&15)).
  __shared__ __align__(16) _Float16 As[BM * 128];   // 16 KB
  __shared__ __align__(16) _Float16 Bs[BN * 128];   // 16 KB
  __shared__ float Gs[BM * GSTR];
  __shared__ float SmallIn[BM * SK];
  __shared__ float W0s[BN * 11];

  const int tid = threadIdx.x;
  const int nb = blockIdx.x, mb = blockIdx.y;
  const int Mbase = mb * BM;

  if (mode < 2) {
    if (tid < BM) {
      int Mg = Mbase + tid;
      float v[SK];
      if (mode == 0) {
        const float* xp = x + ((size_t)Mg * TSEQ + tstep) * IND;
#pragma unroll
        for (int i = 0; i < IND; ++i) v[i] = xp[i];
        const int* ip = xte + ((size_t)Mg * TSEQ + tstep) * 4;
        int i0 = ip[0], i1 = ip[1], i2 = ip[2], i3 = ip[3];
#pragma unroll
        for (int d = 0; d < 3; ++d)
          v[IND + d] = e0[i0 * 3 + d] + e1[i1 * 3 + d] + e2[i2 * 3 + d] + e3[i3 * 3 + d];
      } else {
        const float* yp = yfb + (size_t)Mg * OUTD;
#pragma unroll
        for (int i = 0; i < OUTD; ++i) v[i] = yp[i];
        const int* ip = yte + ((size_t)Mg * PRED + tstep) * 4;
        int i0 = ip[0], i1 = ip[1], i2 = ip[2], i3 = ip[3];
#pragma unroll
        for (int d = 0; d < 3; ++d)
          v[IND + d] = e0[i0 * 3 + d] + e1[i1 * 3 + d] + e2[i2 * 3 + d] + e3[i3 * 3 + d];
      }
#pragma unroll
      for (int i = 0; i < SK; ++i) SmallIn[tid * SK + i] = v[i];
    }
    if (tid < BN) {
      const float* wp = W0p + (size_t)(nb * BN + tid) * SK;
#pragma unroll
      for (int i = 0; i < SK; ++i) W0s[tid * 11 + i] = wp[i];
    }
  }

  const int w = tid >> 6, lane = tid & 63;
  const int quad = lane >> 4, l16 = lane & 15;

  // DMA decomposition: each 1KB issue = 4 rows x 256B; lane -> (dr, ds)
  const int dr = lane >> 4;       // row within issue (0..3)
  const int ds = lane & 15;       // swizzled seg position (0..15)

  size_t a_goff[4], b_goff[4];
  _Float16 *a_lp[4], *b_lp[4];
#pragma unroll
  for (int i = 0; i < 4; ++i) {
    int lrow = w * 16 + i * 4 + dr;           // 0..63
    int sg = ds ^ (i * 4 + dr);               // global seg gathered into slot ds
    a_goff[i] = (size_t)(Mbase + lrow) * HID * 2 + (size_t)sg * 16;
    b_goff[i] = (size_t)(nb * BN + lrow) * (size_t)Kdim * 2 + (size_t)sg * 16;
    a_lp[i] = As + lrow * 128 + ds * 8;
    b_lp[i] = Bs + lrow * 128 + ds * 8;
  }

  f32x4 acc[4] = {};   // wave w owns n-cols [w*16, w*16+16), all 64 m-rows

  for (int kk = 0; kk < Kdim; kk += BK) {
    const char* Abase = (kk < 1024)
        ? ((const char*)A1 + (size_t)kk * 2)
        : ((const char*)A2 + (size_t)(kk - 1024) * 2);
    const char* Bbase = (const char*)Bm + (size_t)kk * 2;
#pragma unroll
    for (int i = 0; i < 4; ++i) {
      async_cp16(Abase + a_goff[i], a_lp[i]);
      async_cp16(Bbase + b_goff[i], b_lp[i]);
    }
    __syncthreads();   // drains vmcnt -> DMA complete, all waves aligned
#pragma unroll
    for (int ks = 0; ks < 4; ++ks) {
      int segq = (ks * 4 + quad) ^ l16;
      f16x8 bf = *reinterpret_cast<const f16x8*>(Bs + (w * 16 + l16) * 128 + segq * 8);
#pragma unroll
      for (int mt = 0; mt < 4; ++mt) {
        f16x8 af = *reinterpret_cast<const f16x8*>(As + (mt * 16 + l16) * 128 + segq * 8);
        acc[mt] = __builtin_amdgcn_mfma_f32_16x16x32_f16(af, bf, acc[mt], 0, 0, 0);
      }
    }
    __syncthreads();   // all fragment reads done before next chunk's DMA
  }

  // acc (C-layout: row = quad*4+r, col = lane&15) -> gates LDS tile
#pragma unroll
  for (int mt = 0; mt < 4; ++mt) {
    int row = mt * 16 + quad * 4;
    int col = w * 16 + l16;
#pragma unroll
    for (int r = 0; r < 4; ++r)
      Gs[(row + r) * GSTR + col] = acc[mt][r];
  }
  __syncthreads();

  // fused cell update: 64 rows x 16 units, 4 (m,u) pairs per thread
#pragma unroll
  for (int i = 0; i < 4; ++i) {
    int m = (tid >> 4) + i * 16;
    int u = tid & 15;
    float gi = Gs[m * GSTR + u];
    float gf = Gs[m * GSTR + 16 + u];
    float gg = Gs[m * GSTR + 32 + u];
    float go = Gs[m * GSTR + 48 + u];
    int nbase = nb * BN;
    gi += biasL[nbase + u];
    gf += biasL[nbase + 16 + u];
    gg += biasL[nbase + 32 + u];
    go += biasL[nbase + 48 + u];
    if (mode < 2) {
#pragma unroll
      for (int k = 0; k < SK; ++k) {
        float sv = SmallIn[m * SK + k];
        gi += sv * W0s[u * 11 + k];
        gf += sv * W0s[(16 + u) * 11 + k];
        gg += sv * W0s[(32 + u) * 11 + k];
        go += sv * W0s[(48 + u) * 11 + k];
      }
    }
    size_t cidx = (size_t)(Mbase + m) * HID + (size_t)nb * 16 + u;
    float cold = cst[cidx];
    float cn = sigmoidf_fast(gf) * cold + sigmoidf_fast(gi) * tanhf_fast(gg);
    float hn = sigmoidf_fast(go) * tanhf_fast(cn);
    cst[cidx] = cn;
    hout[cidx] = (_Float16)hn;
  }
}

// ---------------------------------------------------------------------------
// FC head: y = h2 @ fcW^T + fcb -> d_out[:, s, :] and feedback buffer.
// 64 blocks x 4 waves; one wave per batch row.
// ---------------------------------------------------------------------------
__global__ __launch_bounds__(256) void fc_kernel(
    const _Float16* __restrict__ h2, const float* __restrict__ fcW,
    const float* __restrict__ fcb, float* __restrict__ out,
    float* __restrict__ yfb, int s)
{
  int wv = threadIdx.x >> 6, lane = threadIdx.x & 63;
  int row = blockIdx.x * 4 + wv;
  const _Float16* hp = h2 + (size_t)row * HID + lane * 16;
  float hv[16];
#pragma unroll
  for (int i = 0; i < 16; ++i) hv[i] = (float)hp[i];
  float acc[OUTD];
#pragma unroll
  for (int o = 0; o < OUTD; ++o) {
    const float* wp = fcW + (size_t)o * HID + lane * 16;
    float a = 0.f;
#pragma unroll
    for (int i = 0; i < 16; ++i) a += hv[i] * wp[i];
    acc[o] = a;
  }
#pragma unroll
  for (int o = 0; o < OUTD; ++o)
#pragma unroll
    for (int off = 32; off >= 1; off >>= 1)
      acc[o] += __shfl_xor(acc[o], off, 64);
  if (lane == 0) {
#pragma unroll
    for (int o = 0; o < OUTD; ++o) {
      float v = acc[o] + fcb[o];
      out[(size_t)row * (PRED * OUTD) + s * OUTD + o] = v;
      yfb[row * OUTD + o] = v;
    }
  }
}

// ---------------------------------------------------------------------------
// Workspace layout (bytes):
//   B0      @ 0         : 4096*1024*2 = 8388608
//   B1      @ 8388608   : 4096*2048*2 = 16777216
//   B2      @ 25165824  : 16777216
//   W0p     @ 41943040  : 4096*10*4   = 163840
//   biasP   @ 42106880  : 3*4096*4    = 49152
//   h par0  @ 42156032  : 3*256*1024*2 = 1572864   } zeroed together
//   c       @ 43728896  : 3*256*1024*4 = 3145728   } (4718592 B)
//   h par1  @ 46874624  : 1572864
//   yfb     @ 48447488  : 256*7*4 = 7168
// ---------------------------------------------------------------------------
extern "C" void kernel_launch(void* const* d_in, const int* in_sizes, int n_in,
                              void* d_out, int out_size, void* d_ws, size_t ws_size,
                              hipStream_t stream) {
  const float* x   = (const float*)d_in[0];
  const int*   xte = (const int*)d_in[2];
  const int*   yte = (const int*)d_in[3];
  const float* e0  = (const float*)d_in[4];
  const float* e1  = (const float*)d_in[5];
  const float* e2  = (const float*)d_in[6];
  const float* e3  = (const float*)d_in[7];
  const float* Wih0 = (const float*)d_in[8];
  const float* Whh0 = (const float*)d_in[9];
  const float* bih0 = (const float*)d_in[10];
  const float* bhh0 = (const float*)d_in[11];
  const float* Wih1 = (const float*)d_in[12];
  const float* Whh1 = (const float*)d_in[13];
  const float* bih1 = (const float*)d_in[14];
  const float* bhh1 = (const float*)d_in[15];
  const float* Wih2 = (const float*)d_in[16];
  const float* Whh2 = (const float*)d_in[17];
  const float* bih2 = (const float*)d_in[18];
  const float* bhh2 = (const float*)d_in[19];
  const float* fcW = (const float*)d_in[20];
  const float* fcb = (const float*)d_in[21];
  float* out = (float*)d_out;

  char* ws = (char*)d_ws;
  _Float16* B0   = (_Float16*)(ws);
  _Float16* B1   = (_Float16*)(ws + 8388608);
  _Float16* B2   = (_Float16*)(ws + 25165824);
  float*    W0p  = (float*)(ws + 41943040);
  float*    biasP= (float*)(ws + 42106880);
  char*     hp0  = ws + 42156032;
  float*    cbuf = (float*)(ws + 43728896);
  char*     hp1  = ws + 46874624;
  float*    yfb  = (float*)(ws + 48447488);

  hipMemsetAsync(hp0, 0, 4718592, stream);

  prep_kernel<<<82128, 256, 0, stream>>>(Wih0, Whh0, bih0, bhh0,
                                         Wih1, Whh1, bih1, bhh1,
                                         Wih2, Whh2, bih2, bhh2,
                                         B0, B1, B2, W0p, biasP);

  auto hbuf = [&](int par, int l) -> _Float16* {
    return (_Float16*)((par ? hp1 : hp0) + (size_t)l * 524288);
  };
  float* cl[3] = {cbuf, cbuf + 262144, cbuf + 524288};

  dim3 grid(64, 4), blk(256);
  int p = 0;

  // encoder
  for (int t = 0; t < TSEQ; ++t) {
    lstm_step<<<grid, blk, 0, stream>>>(0, t, 1024, hbuf(p, 0), hbuf(p, 0), B0,
                                        biasP, W0p, cl[0], hbuf(1 - p, 0),
                                        x, xte, yfb, yte, e0, e1, e2, e3);
    lstm_step<<<grid, blk, 0, stream>>>(2, t, 2048, hbuf(1 - p, 0), hbuf(p, 1), B1,
                                        biasP + 4096, W0p, cl[1], hbuf(1 - p, 1),
                                        x, xte, yfb, yte, e0, e1, e2, e3);
    lstm_step<<<grid, blk, 0, stream>>>(2, t, 2048, hbuf(1 - p, 1), hbuf(p, 2), B2,
                                        biasP + 8192, W0p, cl[2], hbuf(1 - p, 2),
                                        x, xte, yfb, yte, e0, e1, e2, e3);
    p ^= 1;
  }

  // decoder
  for (int s = 0; s < PRED; ++s) {
    fc_kernel<<<64, 256, 0, stream>>>(hbuf(p, 2), fcW, fcb, out, yfb, s);
    if (s < PRED - 1) {
      lstm_step<<<grid, blk, 0, stream>>>(1, s, 1024, hbuf(p, 0), hbuf(p, 0), B0,
                                          biasP, W0p, cl[0], hbuf(1 - p, 0),
                                          x, xte, yfb, yte, e0, e1, e2, e3);
      lstm_step<<<grid, blk, 0, stream>>>(2, s, 2048, hbuf(1 - p, 0), hbuf(p, 1), B1,
                                          biasP + 4096, W0p, cl[1], hbuf(1 - p, 1),
                                          x, xte, yfb, yte, e0, e1, e2, e3);
      lstm_step<<<grid, blk, 0, stream>>>(2, s, 2048, hbuf(1 - p, 1), hbuf(p, 2), B2,
                                          biasP + 8192, W0p, cl[2], hbuf(1 - p, 2),
                                          x, xte, yfb, yte, e0, e1, e2, e3);
      p ^= 1;
    }
  }
}

// Round 3
// 8728.306 us; speedup vs baseline: 3.6334x; 1.3839x over previous
//
#include <hip/hip_runtime.h>

#define HID   1024
#define BATCH 256
#define TSEQ  128
#define PRED  96
#define IND   7
#define OUTD  7
#define SK    10   // small input dim: 7 features + 3 time-encode dims

typedef __attribute__((ext_vector_type(8))) _Float16 f16x8;
typedef __attribute__((ext_vector_type(4))) float    f32x4;

#define BM   64
#define BN   64
#define GSTR 68    // gates LDS stride (floats), <=2-way bank aliasing (free)

__device__ __forceinline__ float sigmoidf_fast(float x) {
  return 1.0f / (1.0f + __expf(-x));
}
__device__ __forceinline__ float tanhf_fast(float x) {
  float ax = fabsf(x);
  float e  = __expf(-2.0f * ax);
  float r  = (1.0f - e) / (1.0f + e);
  return copysignf(r, x);
}

__device__ __forceinline__ void async_cp16(const void* g, void* l) {
  __builtin_amdgcn_global_load_lds(
      (const __attribute__((address_space(1))) void*)g,
      (__attribute__((address_space(3))) void*)l, 16, 0, 0);
}

// fine-grained wait + barrier (pipeline): NEVER vmcnt(0) mid-loop
#define WBAR(N) asm volatile("s_waitcnt vmcnt(" #N ")\n\ts_barrier" ::: "memory")
#define BARO()  asm volatile("s_barrier" ::: "memory")

// ---------------------------------------------------------------------------
// Weight prep: fp16 B [n][k], n = nb*64 + gate*16 + u <-> r = gate*1024+nb*16+u
// ---------------------------------------------------------------------------
__global__ __launch_bounds__(256) void prep_kernel(
    const float* __restrict__ Wih0, const float* __restrict__ Whh0,
    const float* __restrict__ bih0, const float* __restrict__ bhh0,
    const float* __restrict__ Wih1, const float* __restrict__ Whh1,
    const float* __restrict__ bih1, const float* __restrict__ bhh1,
    const float* __restrict__ Wih2, const float* __restrict__ Whh2,
    const float* __restrict__ bih2, const float* __restrict__ bhh2,
    _Float16* __restrict__ B0, _Float16* __restrict__ B1, _Float16* __restrict__ B2,
    float* __restrict__ W0p, float* __restrict__ biasP)
{
  size_t e = (size_t)blockIdx.x * 256 + threadIdx.x;
  const size_t S0 = (size_t)4096 * 1024;
  const size_t S1 = (size_t)4096 * 2048;
  if (e < S0) {
    int n = (int)(e >> 10), k = (int)(e & 1023);
    int nb = n >> 6, gate = (n >> 4) & 3, u = n & 15;
    int r = gate * 1024 + nb * 16 + u;
    B0[e] = (_Float16)Whh0[(size_t)r * 1024 + k];
  } else if (e < S0 + S1) {
    size_t q = e - S0;
    int n = (int)(q >> 11), k = (int)(q & 2047);
    int nb = n >> 6, gate = (n >> 4) & 3, u = n & 15;
    int r = gate * 1024 + nb * 16 + u;
    float v = (k < 1024) ? Wih1[(size_t)r * 1024 + k]
                         : Whh1[(size_t)r * 1024 + (k - 1024)];
    B1[q] = (_Float16)v;
  } else if (e < S0 + 2 * S1) {
    size_t q = e - S0 - S1;
    int n = (int)(q >> 11), k = (int)(q & 2047);
    int nb = n >> 6, gate = (n >> 4) & 3, u = n & 15;
    int r = gate * 1024 + nb * 16 + u;
    float v = (k < 1024) ? Wih2[(size_t)r * 1024 + k]
                         : Whh2[(size_t)r * 1024 + (k - 1024)];
    B2[q] = (_Float16)v;
  } else if (e < S0 + 2 * S1 + 40960) {
    int q = (int)(e - S0 - 2 * S1);
    int n = q / 10, k = q - n * 10;
    int nb = n >> 6, gate = (n >> 4) & 3, u = n & 15;
    int r = gate * 1024 + nb * 16 + u;
    W0p[q] = Wih0[(size_t)r * 10 + k];
  } else if (e < S0 + 2 * S1 + 40960 + 12288) {
    int q = (int)(e - S0 - 2 * S1 - 40960);
    int l = q >> 12, n = q & 4095;
    int nb = n >> 6, gate = (n >> 4) & 3, u = n & 15;
    int r = gate * 1024 + nb * 16 + u;
    const float* bi = (l == 0) ? bih0 : (l == 1) ? bih1 : bih2;
    const float* bh = (l == 0) ? bhh0 : (l == 1) ? bhh1 : bhh2;
    biasP[q] = bi[r] + bh[r];
  }
}

// ---------------------------------------------------------------------------
// Encoder wavefront kernel: one dispatch d computes L0@t=d, L1@t=d-1, L2@t=d-2.
// Grid (64 n-tiles, 12 = 4 m-tiles x 3 layers) -> 768 blocks, 3 blocks/CU.
// All layers read parity p=d&1, write 1-p. BK=128 single-buffer staging.
// ---------------------------------------------------------------------------
__global__ __launch_bounds__(256) void lstm_wave(
    int d,
    _Float16* __restrict__ h0p0, _Float16* __restrict__ h0p1,
    _Float16* __restrict__ h1p0, _Float16* __restrict__ h1p1,
    _Float16* __restrict__ h2p0, _Float16* __restrict__ h2p1,
    const _Float16* __restrict__ B0g, const _Float16* __restrict__ B1g,
    const _Float16* __restrict__ B2g,
    const float* __restrict__ biasP, const float* __restrict__ W0p,
    float* __restrict__ c0, float* __restrict__ c1, float* __restrict__ c2,
    const float* __restrict__ x, const int* __restrict__ xte,
    const float* __restrict__ e0, const float* __restrict__ e1,
    const float* __restrict__ e2, const float* __restrict__ e3)
{
  __shared__ __align__(16) char smem[32768];   // As 16K | Bs 16K ; Gs aliased after
  __shared__ float SmallIn[BM * SK];
  __shared__ float W0s[BN * 11];

  const int layer = blockIdx.y >> 2;
  const int mb = blockIdx.y & 3, nb = blockIdx.x;
  const int t = d - layer;
  if (t < 0 || t >= TSEQ) return;
  const int p = d & 1;

  const _Float16 *A1, *A2; _Float16* ho; const _Float16* Bm;
  const float* bias; float* cst; int Kdim;
  if (layer == 0) {
    A1 = p ? h0p1 : h0p0; A2 = A1;              ho = p ? h0p0 : h0p1;
    Bm = B0g; bias = biasP;        cst = c0; Kdim = 1024;
  } else if (layer == 1) {
    A1 = p ? h0p1 : h0p0; A2 = p ? h1p1 : h1p0; ho = p ? h1p0 : h1p1;
    Bm = B1g; bias = biasP + 4096; cst = c1; Kdim = 2048;
  } else {
    A1 = p ? h1p1 : h1p0; A2 = p ? h2p1 : h2p0; ho = p ? h2p0 : h2p1;
    Bm = B2g; bias = biasP + 8192; cst = c2; Kdim = 2048;
  }
  const int Mbase = mb * BM;
  const int tid = threadIdx.x;

  if (layer == 0 && tid < BM) {
    int Mg = Mbase + tid;
    float v[SK];
    const float* xp = x + ((size_t)Mg * TSEQ + t) * IND;
#pragma unroll
    for (int i = 0; i < IND; ++i) v[i] = xp[i];
    const int* ip = xte + ((size_t)Mg * TSEQ + t) * 4;
    int i0 = ip[0], i1 = ip[1], i2 = ip[2], i3 = ip[3];
#pragma unroll
    for (int dd = 0; dd < 3; ++dd)
      v[IND + dd] = e0[i0 * 3 + dd] + e1[i1 * 3 + dd] + e2[i2 * 3 + dd] + e3[i3 * 3 + dd];
#pragma unroll
    for (int i = 0; i < SK; ++i) SmallIn[tid * SK + i] = v[i];
    const float* wp = W0p + (size_t)(nb * BN + tid) * SK;
#pragma unroll
    for (int i = 0; i < SK; ++i) W0s[tid * 11 + i] = wp[i];
  }

  _Float16* As = (_Float16*)smem;
  _Float16* Bs = (_Float16*)(smem + 16384);

  const int w = tid >> 6, lane = tid & 63;
  const int quad = lane >> 4, l16 = lane & 15;
  const int dr = lane >> 4, ds = lane & 15;   // BK=128: 16 segs of 16B per row

  size_t a_goff[4], b_goff[4];
  int lds_off[4];
#pragma unroll
  for (int i = 0; i < 4; ++i) {
    int lrow = w * 16 + i * 4 + dr;
    int sg = ds ^ (i * 4 + dr);
    a_goff[i] = (size_t)(Mbase + lrow) * (HID * 2) + (size_t)sg * 16;
    b_goff[i] = (size_t)(nb * BN + lrow) * ((size_t)Kdim * 2) + (size_t)sg * 16;
    lds_off[i] = lrow * 256 + ds * 16;
  }

  f32x4 acc[4] = {};

  for (int kk = 0; kk < Kdim; kk += 128) {
    const char* Abase = (kk < 1024)
        ? ((const char*)A1 + (size_t)kk * 2)
        : ((const char*)A2 + (size_t)(kk - 1024) * 2);
    const char* Bbase = (const char*)Bm + (size_t)kk * 2;
#pragma unroll
    for (int i = 0; i < 4; ++i) {
      async_cp16(Abase + a_goff[i], smem + lds_off[i]);
      async_cp16(Bbase + b_goff[i], smem + 16384 + lds_off[i]);
    }
    __syncthreads();
#pragma unroll
    for (int ks = 0; ks < 4; ++ks) {
      int segq = (ks * 4 + quad) ^ l16;
      f16x8 bf = *reinterpret_cast<const f16x8*>(Bs + (w * 16 + l16) * 128 + segq * 8);
#pragma unroll
      for (int mt = 0; mt < 4; ++mt) {
        f16x8 af = *reinterpret_cast<const f16x8*>(As + (mt * 16 + l16) * 128 + segq * 8);
        acc[mt] = __builtin_amdgcn_mfma_f32_16x16x32_f16(af, bf, acc[mt], 0, 0, 0);
      }
    }
    __syncthreads();
  }

  float* Gs = (float*)smem;   // alias: all fragment reads done (loop-end sync)
#pragma unroll
  for (int mt = 0; mt < 4; ++mt) {
    int row = mt * 16 + quad * 4;
    int col = w * 16 + l16;
#pragma unroll
    for (int r = 0; r < 4; ++r)
      Gs[(row + r) * GSTR + col] = acc[mt][r];
  }
  __syncthreads();

#pragma unroll
  for (int i = 0; i < 4; ++i) {
    int m = (tid >> 4) + i * 16;
    int u = tid & 15;
    float gi = Gs[m * GSTR + u];
    float gf = Gs[m * GSTR + 16 + u];
    float gg = Gs[m * GSTR + 32 + u];
    float go = Gs[m * GSTR + 48 + u];
    int nbase = nb * BN;
    gi += bias[nbase + u];
    gf += bias[nbase + 16 + u];
    gg += bias[nbase + 32 + u];
    go += bias[nbase + 48 + u];
    if (layer == 0) {
#pragma unroll
      for (int k = 0; k < SK; ++k) {
        float sv = SmallIn[m * SK + k];
        gi += sv * W0s[u * 11 + k];
        gf += sv * W0s[(16 + u) * 11 + k];
        gg += sv * W0s[(32 + u) * 11 + k];
        go += sv * W0s[(48 + u) * 11 + k];
      }
    }
    size_t cidx = (size_t)(Mbase + m) * HID + (size_t)nb * 16 + u;
    float cold = cst[cidx];
    float cn = sigmoidf_fast(gf) * cold + sigmoidf_fast(gi) * tanhf_fast(gg);
    float hn = sigmoidf_fast(go) * tanhf_fast(cn);
    cst[cidx] = cn;
    ho[cidx] = (_Float16)hn;
  }
}

// ---------------------------------------------------------------------------
// Decoder pipelined layer-step. BK=64 chunks, 3 LDS buffers, depth-2 prefetch,
// raw s_waitcnt vmcnt(N)+s_barrier (never vmcnt(0) mid-loop).
// MODE 1: L0 (small input from out[:,s,:] + yte). MODE 2: deep.
// MODE 3: deep + fused fc epilogue -> atomicAdd out[:,s+1,:].
// Grid (64,4), 256 thr, 1 block/CU.
// ---------------------------------------------------------------------------
template<int KCH, int MODE>
__global__ __launch_bounds__(256) void lstm_pipe(
    int s,
    const _Float16* __restrict__ A1, const _Float16* __restrict__ A2,
    const _Float16* __restrict__ Bm, const float* __restrict__ biasL,
    const float* __restrict__ W0p,
    float* __restrict__ cst, _Float16* __restrict__ hout,
    float* __restrict__ out, const int* __restrict__ yte,
    const float* __restrict__ e0, const float* __restrict__ e1,
    const float* __restrict__ e2, const float* __restrict__ e3,
    const float* __restrict__ fcW, const float* __restrict__ fcb)
{
  __shared__ __align__(16) char smem[3 * 16384];   // 3 bufs: A 8K | B 8K each
  __shared__ float SmallIn[BM * SK];
  __shared__ float W0s[BN * 11];

  const int tid = threadIdx.x;
  const int nb = blockIdx.x, mb = blockIdx.y;
  const int Mbase = mb * BM;

  if (MODE == 1 && tid < BM) {
    int Mg = Mbase + tid;
    float v[SK];
    const float* yp = out + (size_t)Mg * (PRED * OUTD) + s * OUTD;
#pragma unroll
    for (int i = 0; i < OUTD; ++i) v[i] = yp[i];
    const int* ip = yte + ((size_t)Mg * PRED + s) * 4;
    int i0 = ip[0], i1 = ip[1], i2 = ip[2], i3 = ip[3];
#pragma unroll
    for (int dd = 0; dd < 3; ++dd)
      v[IND + dd] = e0[i0 * 3 + dd] + e1[i1 * 3 + dd] + e2[i2 * 3 + dd] + e3[i3 * 3 + dd];
#pragma unroll
    for (int i = 0; i < SK; ++i) SmallIn[tid * SK + i] = v[i];
    const float* wp = W0p + (size_t)(nb * BN + tid) * SK;
#pragma unroll
    for (int i = 0; i < SK; ++i) W0s[tid * 11 + i] = wp[i];
  }

  const int w = tid >> 6, lane = tid & 63;
  const int quad = lane >> 4, l16 = lane & 15;
  const int dr = lane >> 3, ds = lane & 7;   // BK=64: 8 segs of 16B per row

  // per-chunk: A 64rows x 128B (8KB), B same. 4 DMA issues/wave/chunk.
  size_t a_goff[2], b_goff[2];
  int lds_off[2];
#pragma unroll
  for (int i = 0; i < 2; ++i) {
    int lrow = w * 16 + i * 8 + dr;           // lrow&7 == dr
    int sg = ds ^ dr;                         // seg swizzle folded into gather
    a_goff[i] = (size_t)(Mbase + lrow) * (HID * 2) + (size_t)sg * 16;
    b_goff[i] = (size_t)(nb * BN + lrow) * ((size_t)KCH * 128) + (size_t)sg * 16;
    lds_off[i] = lrow * 128 + ds * 16;
  }

  f32x4 acc[4] = {};

  __syncthreads();   // vmcnt=0 for every wave before pipeline starts

#define ISSUE(c) do { \
    const char* Ab_ = (KCH == 16 || (c) < 16) \
        ? ((const char*)A1 + (size_t)(c) * 128) \
        : ((const char*)A2 + (size_t)((c) - 16) * 128); \
    const char* Bb_ = (const char*)Bm + (size_t)(c) * 128; \
    char* Lb_ = smem + ((c) % 3) * 16384; \
    _Pragma("unroll") \
    for (int i_ = 0; i_ < 2; ++i_) { \
      async_cp16(Ab_ + a_goff[i_], Lb_ + lds_off[i_]); \
      async_cp16(Bb_ + b_goff[i_], Lb_ + 8192 + lds_off[i_]); \
    } } while (0)

  ISSUE(0);
  ISSUE(1);
#pragma unroll
  for (int c = 0; c < KCH; ++c) {
    if (c + 2 < KCH) { ISSUE(c + 2); WBAR(8); }
    else if (c + 2 == KCH) { WBAR(4); }
    else { WBAR(0); }
    {
      const _Float16* As = (const _Float16*)(smem + (c % 3) * 16384);
      const _Float16* Bs = As + 4096;
#pragma unroll
      for (int ks = 0; ks < 2; ++ks) {
        int g = ks * 4 + quad;
        int sp = g ^ (l16 & 7);
        f16x8 bf = *reinterpret_cast<const f16x8*>(Bs + (w * 16 + l16) * 64 + sp * 8);
#pragma unroll
        for (int mt = 0; mt < 4; ++mt) {
          f16x8 af = *reinterpret_cast<const f16x8*>(As + (mt * 16 + l16) * 64 + sp * 8);
          acc[mt] = __builtin_amdgcn_mfma_f32_16x16x32_f16(af, bf, acc[mt], 0, 0, 0);
        }
      }
    }
    BARO();   // buffer-recycle barrier (3-buffer rotation needs it)
  }
#undef ISSUE

  __syncthreads();
  float* Gs = (float*)smem;
#pragma unroll
  for (int mt = 0; mt < 4; ++mt) {
    int row = mt * 16 + quad * 4;
    int col = w * 16 + l16;
#pragma unroll
    for (int r = 0; r < 4; ++r)
      Gs[(row + r) * GSTR + col] = acc[mt][r];
  }
  __syncthreads();

  float w7[OUTD];
  if (MODE == 3) {
#pragma unroll
    for (int o = 0; o < OUTD; ++o)
      w7[o] = fcW[(size_t)o * HID + nb * 16 + (tid & 15)];
  }

#pragma unroll
  for (int i = 0; i < 4; ++i) {
    int m = (tid >> 4) + i * 16;
    int u = tid & 15;
    float gi = Gs[m * GSTR + u];
    float gf = Gs[m * GSTR + 16 + u];
    float gg = Gs[m * GSTR + 32 + u];
    float go = Gs[m * GSTR + 48 + u];
    int nbase = nb * BN;
    gi += biasL[nbase + u];
    gf += biasL[nbase + 16 + u];
    gg += biasL[nbase + 32 + u];
    go += biasL[nbase + 48 + u];
    if (MODE == 1) {
#pragma unroll
      for (int k = 0; k < SK; ++k) {
        float sv = SmallIn[m * SK + k];
        gi += sv * W0s[u * 11 + k];
        gf += sv * W0s[(16 + u) * 11 + k];
        gg += sv * W0s[(32 + u) * 11 + k];
        go += sv * W0s[(48 + u) * 11 + k];
      }
    }
    size_t cidx = (size_t)(Mbase + m) * HID + (size_t)nb * 16 + u;
    float cold = cst[cidx];
    float cn = sigmoidf_fast(gf) * cold + sigmoidf_fast(gi) * tanhf_fast(gg);
    float hn = sigmoidf_fast(go) * tanhf_fast(cn);
    cst[cidx] = cn;
    hout[cidx] = (_Float16)hn;

    if (MODE == 3) {
      // partial y for this block's 16-unit slice; reduce over u (16 lanes)
#pragma unroll
      for (int o = 0; o < OUTD; ++o) {
        float r = hn * w7[o];
        r += __shfl_xor(r, 1, 16);
        r += __shfl_xor(r, 2, 16);
        r += __shfl_xor(r, 4, 16);
        r += __shfl_xor(r, 8, 16);
        if (u == 0) {
          float val = r + ((nb == 0) ? fcb[o] : 0.0f);
          atomicAdd(&out[(size_t)(Mbase + m) * (PRED * OUTD) + (s + 1) * OUTD + o], val);
        }
      }
    }
  }
}

// ---------------------------------------------------------------------------
// Standalone FC head for y0 only: y = h2 @ fcW^T + fcb -> out[:,0,:].
// ---------------------------------------------------------------------------
__global__ __launch_bounds__(256) void fc_kernel(
    const _Float16* __restrict__ h2, const float* __restrict__ fcW,
    const float* __restrict__ fcb, float* __restrict__ out)
{
  int wv = threadIdx.x >> 6, lane = threadIdx.x & 63;
  int row = blockIdx.x * 4 + wv;
  const _Float16* hp = h2 + (size_t)row * HID + lane * 16;
  float hv[16];
#pragma unroll
  for (int i = 0; i < 16; ++i) hv[i] = (float)hp[i];
  float acc[OUTD];
#pragma unroll
  for (int o = 0; o < OUTD; ++o) {
    const float* wp = fcW + (size_t)o * HID + lane * 16;
    float a = 0.f;
#pragma unroll
    for (int i = 0; i < 16; ++i) a += hv[i] * wp[i];
    acc[o] = a;
  }
#pragma unroll
  for (int o = 0; o < OUTD; ++o)
#pragma unroll
    for (int off = 32; off >= 1; off >>= 1)
      acc[o] += __shfl_xor(acc[o], off, 64);
  if (lane == 0) {
#pragma unroll
    for (int o = 0; o < OUTD; ++o)
      out[(size_t)row * (PRED * OUTD) + o] = acc[o] + fcb[o];
  }
}

// ---------------------------------------------------------------------------
// Workspace layout (bytes):
//   B0 @0 (8 MB) | B1 @8388608 (16 MB) | B2 @25165824 (16 MB)
//   W0p @41943040 | biasP @42106880
//   h par0 @42156032 (1.5 MB) + c @43728896 (3 MB)  } one memset
//   h par1 @46874624 (1.5 MB)                        } second memset
// ---------------------------------------------------------------------------
extern "C" void kernel_launch(void* const* d_in, const int* in_sizes, int n_in,
                              void* d_out, int out_size, void* d_ws, size_t ws_size,
                              hipStream_t stream) {
  const float* x   = (const float*)d_in[0];
  const int*   xte = (const int*)d_in[2];
  const int*   yte = (const int*)d_in[3];
  const float* e0  = (const float*)d_in[4];
  const float* e1  = (const float*)d_in[5];
  const float* e2  = (const float*)d_in[6];
  const float* e3  = (const float*)d_in[7];
  const float* Wih0 = (const float*)d_in[8];
  const float* Whh0 = (const float*)d_in[9];
  const float* bih0 = (const float*)d_in[10];
  const float* bhh0 = (const float*)d_in[11];
  const float* Wih1 = (const float*)d_in[12];
  const float* Whh1 = (const float*)d_in[13];
  const float* bih1 = (const float*)d_in[14];
  const float* bhh1 = (const float*)d_in[15];
  const float* Wih2 = (const float*)d_in[16];
  const float* Whh2 = (const float*)d_in[17];
  const float* bih2 = (const float*)d_in[18];
  const float* bhh2 = (const float*)d_in[19];
  const float* fcW = (const float*)d_in[20];
  const float* fcb = (const float*)d_in[21];
  float* out = (float*)d_out;

  char* ws = (char*)d_ws;
  _Float16* B0   = (_Float16*)(ws);
  _Float16* B1   = (_Float16*)(ws + 8388608);
  _Float16* B2   = (_Float16*)(ws + 25165824);
  float*    W0p  = (float*)(ws + 41943040);
  float*    biasP= (float*)(ws + 42106880);
  char*     hp0  = ws + 42156032;
  float*    cbuf = (float*)(ws + 43728896);
  char*     hp1  = ws + 46874624;

  // zero: out (atomic targets), h par0 + c (contiguous), h par1
  hipMemsetAsync(out, 0, (size_t)out_size * 4, stream);
  hipMemsetAsync(hp0, 0, 4718592, stream);
  hipMemsetAsync(hp1, 0, 1572864, stream);

  prep_kernel<<<82128, 256, 0, stream>>>(Wih0, Whh0, bih0, bhh0,
                                         Wih1, Whh1, bih1, bhh1,
                                         Wih2, Whh2, bih2, bhh2,
                                         B0, B1, B2, W0p, biasP);

  auto hb = [&](int l, int par) -> _Float16* {
    return (_Float16*)((par ? hp1 : hp0) + (size_t)l * 524288);
  };
  float* cl[3] = {cbuf, cbuf + 262144, cbuf + 524288};

  // encoder: wavefront over (layer, t) diagonals
  for (int d = 0; d < TSEQ + 2; ++d) {
    lstm_wave<<<dim3(64, 12), 256, 0, stream>>>(
        d, hb(0,0), hb(0,1), hb(1,0), hb(1,1), hb(2,0), hb(2,1),
        B0, B1, B2, biasP, W0p, cl[0], cl[1], cl[2],
        x, xte, e0, e1, e2, e3);
  }

  // handoff parities: h0@127 -> par0, h1@127 -> par1, h2@127 -> par0
  _Float16* hr0 = hb(0,0); _Float16* hw0 = hb(0,1);
  _Float16* hr1 = hb(1,1); _Float16* hw1 = hb(1,0);
  _Float16* hr2 = hb(2,0); _Float16* hw2 = hb(2,1);

  fc_kernel<<<64, 256, 0, stream>>>(hr2, fcW, fcb, out);   // y0

  dim3 dgrid(64, 4), blk(256);
  for (int s = 0; s < PRED - 1; ++s) {
    lstm_pipe<16, 1><<<dgrid, blk, 0, stream>>>(
        s, hr0, hr0, B0, biasP, W0p, cl[0], hw0,
        out, yte, e0, e1, e2, e3, fcW, fcb);
    lstm_pipe<32, 2><<<dgrid, blk, 0, stream>>>(
        s, hw0, hr1, B1, biasP + 4096, W0p, cl[1], hw1,
        out, yte, e0, e1, e2, e3, fcW, fcb);
    lstm_pipe<32, 3><<<dgrid, blk, 0, stream>>>(
        s, hw1, hr2, B2, biasP + 8192, W0p, cl[2], hw2,
        out, yte, e0, e1, e2, e3, fcW, fcb);
    _Float16* tmp;
    tmp = hr0; hr0 = hw0; hw0 = tmp;
    tmp = hr1; hr1 = hw1; hw1 = tmp;
    tmp = hr2; hr2 = hw2; hw2 = tmp;
  }
}